// Round 9
// baseline (795.567 us; speedup 1.0000x reference)
//
#include <hip/hip_runtime.h>
#include <hip/hip_bf16.h>
#include <cstddef>
#include <cstdint>

#define NN 150000
#define EP 400000
#define EN 200000
#define SCAN_BS 256

typedef __bf16 bf16x8 __attribute__((ext_vector_type(8)));
typedef float  f32x4  __attribute__((ext_vector_type(4)));

__device__ __forceinline__ float fast_tanh(float x) {
    float e = __expf(2.f * x);
    return 1.f - 2.f / (e + 1.f);
}

// async global->LDS 16B copy (no VGPR round trip; tracked by vmcnt)
__device__ __forceinline__ void async16(const void* g, void* l) {
    __builtin_amdgcn_global_load_lds(
        (const __attribute__((address_space(1))) void*)g,
        (__attribute__((address_space(3))) void*)l, 16, 0, 0);
}

// ---------------- counts ----------------
__global__ void count_kernel(const int* __restrict__ dst, int E, int* __restrict__ cnt) {
    int e = blockIdx.x * blockDim.x + threadIdx.x;
    if (e < E) atomicAdd(&cnt[dst[e]], 1);
}

// ---------------- exclusive scan (3-kernel) ----------------
__global__ void scan_block(const int* __restrict__ cnt, int n,
                           int* __restrict__ excl, int* __restrict__ bsum) {
    __shared__ int lds[SCAN_BS];
    int tid = threadIdx.x;
    int i = blockIdx.x * SCAN_BS + tid;
    int v = (i < n) ? cnt[i] : 0;
    lds[tid] = v;
    __syncthreads();
    for (int d = 1; d < SCAN_BS; d <<= 1) {
        int t = (tid >= d) ? lds[tid - d] : 0;
        __syncthreads();
        lds[tid] += t;
        __syncthreads();
    }
    if (i < n) excl[i] = lds[tid] - v;
    if (tid == SCAN_BS - 1) bsum[blockIdx.x] = lds[tid];
}

__global__ void scan_bsum(int* __restrict__ bsum, int nb) {
    __shared__ int lds[SCAN_BS];
    __shared__ int carry;
    int tid = threadIdx.x;
    if (tid == 0) carry = 0;
    __syncthreads();
    for (int base = 0; base < nb; base += SCAN_BS) {
        int i = base + tid;
        int v = (i < nb) ? bsum[i] : 0;
        lds[tid] = v;
        __syncthreads();
        for (int d = 1; d < SCAN_BS; d <<= 1) {
            int t = (tid >= d) ? lds[tid - d] : 0;
            __syncthreads();
            lds[tid] += t;
            __syncthreads();
        }
        if (i < nb) bsum[i] = lds[tid] - v + carry;
        __syncthreads();
        if (tid == 0) carry += lds[SCAN_BS - 1];
        __syncthreads();
    }
}

__global__ void scan_add(const int* __restrict__ bsum, int n,
                         int* __restrict__ excl, int* __restrict__ cur) {
    int i = blockIdx.x * SCAN_BS + threadIdx.x;
    if (i < n) {
        int o = excl[i] + bsum[blockIdx.x];
        excl[i] = o;
        cur[i] = o;
    }
}

__global__ void fill_csr(const int* __restrict__ src, const int* __restrict__ dst, int E,
                         int* __restrict__ cur, int* __restrict__ csr) {
    int e = blockIdx.x * blockDim.x + threadIdx.x;
    if (e < E) {
        int d = dst[e];
        int p = atomicAdd(&cur[d], 1);
        csr[p] = src[e];
    }
}

// ---------------- vectorized CSR gather means (bf16x8 per lane) ----------------
__global__ void gather1v(const __hip_bfloat16* __restrict__ U1,
                         const int* __restrict__ offp, const int* __restrict__ cntp,
                         const int* __restrict__ csrp,
                         const int* __restrict__ offn, const int* __restrict__ cntn,
                         const int* __restrict__ csrn,
                         float* __restrict__ out) {
    int gid = blockIdx.x * blockDim.x + threadIdx.x;
    if (gid >= NN * 16) return;
    int d = gid >> 4, cg = gid & 15;
    int c0 = cg * 8;
    const int* off; const int* cnt; const int* csr;
    if (cg < 8) { off = offp; cnt = cntp; csr = csrp; }
    else        { off = offn; cnt = cntn; csr = csrn; }
    int o = off[d], dg = cnt[d];
    float acc[8] = {0.f, 0.f, 0.f, 0.f, 0.f, 0.f, 0.f, 0.f};
    for (int e = 0; e < dg; ++e) {
        int s = csr[o + e];
        bf16x8 v = *reinterpret_cast<const bf16x8*>(&U1[(size_t)s * 128 + c0]);
#pragma unroll
        for (int j = 0; j < 8; ++j) acc[j] += (float)v[j];
    }
    float inv = 1.f / (float)(dg > 0 ? dg : 1);
    float4 o0 = make_float4(acc[0] * inv, acc[1] * inv, acc[2] * inv, acc[3] * inv);
    float4 o1 = make_float4(acc[4] * inv, acc[5] * inv, acc[6] * inv, acc[7] * inv);
    *reinterpret_cast<float4*>(&out[(size_t)d * 128 + c0 + 0]) = o0;
    *reinterpret_cast<float4*>(&out[(size_t)d * 128 + c0 + 4]) = o1;
}

__global__ void gather2v(const __hip_bfloat16* __restrict__ z1,
                         const int* __restrict__ offp, const int* __restrict__ cntp,
                         const int* __restrict__ csrp,
                         const int* __restrict__ offn, const int* __restrict__ cntn,
                         const int* __restrict__ csrn,
                         __hip_bfloat16* __restrict__ P, __hip_bfloat16* __restrict__ Q) {
    int gid = blockIdx.x * blockDim.x + threadIdx.x;
    if (gid >= NN * 32) return;
    int d = gid >> 5, cg = gid & 31;
    const int* off; const int* cnt; const int* csr; __hip_bfloat16* out; int c0;
    if (cg < 16) { off = offp; cnt = cntp; csr = csrp; out = P; c0 = cg * 8; }
    else         { off = offn; cnt = cntn; csr = csrn; out = Q; c0 = (cg - 16) * 8; }
    int o = off[d], dg = cnt[d];
    float acc[8] = {0.f, 0.f, 0.f, 0.f, 0.f, 0.f, 0.f, 0.f};
    for (int e = 0; e < dg; ++e) {
        int s = csr[o + e];
        bf16x8 v = *reinterpret_cast<const bf16x8*>(&z1[(size_t)s * 128 + c0]);
#pragma unroll
        for (int j = 0; j < 8; ++j) acc[j] += (float)v[j];
    }
    float inv = 1.f / (float)(dg > 0 ? dg : 1);
    bf16x8 r;
#pragma unroll
    for (int j = 0; j < 8; ++j) r[j] = (__bf16)(acc[j] * inv);
    *reinterpret_cast<bf16x8*>(&out[(size_t)d * 128 + c0]) = r;
}

// ---------------- weight prep ----------------
__global__ void prep_weights(const float* __restrict__ W_in,
                             const float* __restrict__ W1p, const float* __restrict__ b1p,
                             const float* __restrict__ W1n, const float* __restrict__ b1n,
                             const float* __restrict__ W2p, const float* __restrict__ b2p,
                             const float* __restrict__ W2n, const float* __restrict__ b2n,
                             const float* __restrict__ Wz,  const float* __restrict__ Wm1,
                             const float* __restrict__ Wm2,
                             __hip_bfloat16* __restrict__ WtIn,  // [128][64]
                             __hip_bfloat16* __restrict__ WtC1,  // [128][128]
                             __hip_bfloat16* __restrict__ WtL1,  // [128][128]
                             __hip_bfloat16* __restrict__ Wt2,   // [128][384]
                             __hip_bfloat16* __restrict__ WtZ,
                             __hip_bfloat16* __restrict__ WtM1,
                             __hip_bfloat16* __restrict__ WtM2,
                             float* __restrict__ bcat1, float* __restrict__ b2cat) {
    int idx = blockIdx.x * blockDim.x + threadIdx.x;
    if (idx < 128 * 64) {
        int c = idx >> 6, k = idx & 63;
        WtIn[idx] = __float2bfloat16(W_in[k * 128 + c]);
    }
    if (idx < 128 * 128) {
        int c = idx >> 7, k = idx & 127;
        float v1 = (c < 64) ? W1p[k * 64 + c] : W1n[k * 64 + (c - 64)];
        WtC1[idx] = __float2bfloat16(v1);
        float v2 = (c < 64) ? W1p[(128 + k) * 64 + c] : W1n[(128 + k) * 64 + (c - 64)];
        WtL1[idx] = __float2bfloat16(v2);
        WtZ[idx]  = __float2bfloat16(Wz[k * 128 + c]);
        WtM1[idx] = __float2bfloat16(Wm1[k * 128 + c]);
        WtM2[idx] = __float2bfloat16(Wm2[k * 128 + c]);
    }
    if (idx < 128 * 384) {
        int c = idx / 384, r = idx % 384;
        float v = 0.f;
        if (r < 64)       { if (c < 64)  v = W2p[r * 64 + c]; }
        else if (r < 128) { if (c >= 64) v = W2n[(r - 64) * 64 + (c - 64)]; }
        else if (r < 192) { if (c >= 64) v = W2n[(64 + r - 128) * 64 + (c - 64)]; }
        else if (r < 256) { if (c < 64)  v = W2p[(64 + r - 192) * 64 + c]; }
        else if (r < 320) { if (c < 64)  v = W2p[(128 + r - 256) * 64 + c]; }
        else              { if (c >= 64) v = W2n[(128 + r - 320) * 64 + (c - 64)]; }
        Wt2[idx] = __float2bfloat16(v);
    }
    if (idx < 128) {
        bcat1[idx] = (idx < 64) ? b1p[idx] : b1n[idx - 64];
        b2cat[idx] = (idx < 64) ? b2p[idx] : b2n[idx - 64];
    }
}

// ================= LDS-staged MFMA GEMM: 32 rows/wave, 128-row tiles =================
// W staged via global_load_lds (async, no VGPR round trip) in FRAGMENT order:
// slot = (c*NFC+kk)*64 + lane -> per staging instr the wave writes 1024 contiguous
// LDS bytes (wave-uniform base + lane*16, exactly the HW pattern).
// TPB tiles per block; tile1's A loads issued right after the barrier so they
// overlap tile0's MFMA+epilogue.
template<int K, int NSEG, int TPB, bool AF32, bool BIAS, bool TANH_ACT, bool ADDEND,
         bool BNIN, bool STATS, bool STOREF, bool STOREB>
__global__ __launch_bounds__(256, 4) void sgemm(
    const void* __restrict__ A0, const void* __restrict__ A1, const void* __restrict__ A2,
    const __hip_bfloat16* __restrict__ Wt,   // [128][K]
    const float* __restrict__ bias,
    const float* __restrict__ addend,        // n x 128 f32
    const float* __restrict__ scale, const float* __restrict__ shift,
    double* __restrict__ stats,
    float* __restrict__ outf, __hip_bfloat16* __restrict__ outb, int n)
{
    constexpr int CHUNK = (K < 128) ? K : 128;
    constexpr int NCH = K / CHUNK;           // >1 only with TPB==1
    constexpr int NFC = CHUNK / 32;          // A frags per chunk (2 or 4)
    constexpr int SEGW = K / NSEG;           // A segment row width
    constexpr int SLOTS = 8 * NFC * 64;      // 16B fragment slots in LDS
    __shared__ __align__(16) char wlds[CHUNK * 256];
    __shared__ float ssum[128], ssq[128];
    const int tid = threadIdx.x, lane = tid & 63, wid = tid >> 6;
    const int l16 = lane & 15, lhi = lane >> 4;

    if (STATS) {
        if (tid < 128) { ssum[tid] = 0.f; ssq[tid] = 0.f; }
    }

    auto stage = [&](int ch) {
#pragma unroll
        for (int i = 0; i < SLOTS / 256; ++i) {
            int slot = tid + i * 256;
            int ln = slot & 63, f = slot >> 6;
            int c = f / NFC, kk = f - c * NFC;
            int row = c * 16 + (ln & 15);
            int gk = ch * CHUNK + kk * 32 + (ln >> 4) * 8;
            async16(Wt + (size_t)row * K + gk, wlds + slot * 16);
        }
    };

    auto lda = [&](int tl, int ch, bf16x8 (&afr)[NFC][2]) {
        const void* Aseg = (NSEG == 1) ? A0 : ((ch == 0) ? A0 : (ch == 1) ? A1 : A2);
        const int kbase = (NSEG == 1) ? ch * CHUNK : 0;
        const int brow = tl * 128 + wid * 32;
#pragma unroll
        for (int kk = 0; kk < NFC; ++kk)
#pragma unroll
            for (int t = 0; t < 2; ++t) {
                int row = brow + t * 16 + l16; if (row > n - 1) row = n - 1;
                if (AF32) {
                    const float* p = (const float*)Aseg + (size_t)row * SEGW + kbase + kk * 32 + lhi * 8;
                    float4 u0 = *reinterpret_cast<const float4*>(p);
                    float4 u1 = *reinterpret_cast<const float4*>(p + 4);
                    bf16x8 a;
                    a[0] = (__bf16)u0.x; a[1] = (__bf16)u0.y; a[2] = (__bf16)u0.z; a[3] = (__bf16)u0.w;
                    a[4] = (__bf16)u1.x; a[5] = (__bf16)u1.y; a[6] = (__bf16)u1.z; a[7] = (__bf16)u1.w;
                    afr[kk][t] = a;
                } else {
                    bf16x8 a = *reinterpret_cast<const bf16x8*>(
                        (const __hip_bfloat16*)Aseg + (size_t)row * SEGW + kbase + kk * 32 + lhi * 8);
                    if (BNIN) {
#pragma unroll
                        for (int j = 0; j < 8; ++j) {
                            int k = kk * 32 + lhi * 8 + j;
                            a[j] = (__bf16)fmaxf((float)a[j] * scale[k] + shift[k], 0.f);
                        }
                    }
                    afr[kk][t] = a;
                }
            }
    };

    auto zacc = [&](f32x4 (&acc)[2][8]) {
#pragma unroll
        for (int t = 0; t < 2; ++t)
#pragma unroll
            for (int c = 0; c < 8; ++c)
#pragma unroll
                for (int i = 0; i < 4; ++i) acc[t][c][i] = 0.f;
    };

    auto domfma = [&](const bf16x8 (&afr)[NFC][2], f32x4 (&acc)[2][8]) {
#pragma unroll
        for (int kk = 0; kk < NFC; ++kk)
#pragma unroll
            for (int c = 0; c < 8; ++c) {
                bf16x8 b = *reinterpret_cast<const bf16x8*>(
                    wlds + (((c * NFC + kk) * 64 + lane) << 4));
                acc[0][c] = __builtin_amdgcn_mfma_f32_16x16x32_bf16(afr[kk][0], b, acc[0][c], 0, 0, 0);
                acc[1][c] = __builtin_amdgcn_mfma_f32_16x16x32_bf16(afr[kk][1], b, acc[1][c], 0, 0, 0);
            }
    };

    auto epi = [&](int tl, f32x4 (&acc)[2][8]) {
        const int brow = tl * 128 + wid * 32;
#pragma unroll
        for (int t = 0; t < 2; ++t)
#pragma unroll
            for (int c = 0; c < 8; ++c) {
                const int col = c * 16 + l16;
                const float bv = BIAS ? bias[col] : 0.f;
                float s = 0.f, q = 0.f;
#pragma unroll
                for (int r = 0; r < 4; ++r) {
                    int grow = brow + t * 16 + lhi * 4 + r;
                    bool ok = grow < n;
                    float v = acc[t][c][r] + bv;
                    if (ADDEND) { if (ok) v += addend[(size_t)grow * 128 + col]; }
                    if (TANH_ACT) v = fast_tanh(v);
                    if (ok) {
                        if (STOREF) outf[(size_t)grow * 128 + col] = v;
                        if (STOREB) outb[(size_t)grow * 128 + col] = __float2bfloat16(v);
                        if (STATS) { s += v; q += v * v; }
                    }
                }
                if (STATS) { atomicAdd(&ssum[col], s); atomicAdd(&ssq[col], q); }
            }
    };

    f32x4 acc[2][8];
    if (NCH == 1) {
        const int tile0 = blockIdx.x * TPB;
        bf16x8 a0[NFC][2];
        stage(0);
        lda(tile0, 0, a0);
        __syncthreads();                       // drains async staging + a0 loads
        if (TPB == 2) {
            bf16x8 a1[NFC][2];
            lda(tile0 + 1, 0, a1);             // overlaps tile0 MFMA + epilogue
            zacc(acc); domfma(a0, acc); epi(tile0, acc);
            zacc(acc); domfma(a1, acc); epi(tile0 + 1, acc);
        } else {
            zacc(acc); domfma(a0, acc); epi(tile0, acc);
        }
    } else {
        const int tile0 = blockIdx.x;
        bf16x8 a0[NFC][2];
        zacc(acc);
#pragma unroll
        for (int ch = 0; ch < NCH; ++ch) {
            stage(ch);
            lda(tile0, ch, a0);
            __syncthreads();                   // staging + A drained
            domfma(a0, acc);
            if (ch != NCH - 1) __syncthreads();// LDS reads done before restage
        }
        epi(tile0, acc);
    }

    if (STATS) {
        __syncthreads();
        if (tid < 128) {
            atomicAdd(&stats[tid],       (double)ssum[tid]);
            atomicAdd(&stats[128 + tid], (double)ssq[tid]);
        }
    }
}

// BN finalize -> scale/shift form: relu(a*scale + shift)
__global__ void bn_finalize(const double* __restrict__ stats,
                            const float* __restrict__ g, const float* __restrict__ be,
                            float* __restrict__ scale, float* __restrict__ shift, int n) {
    int c = threadIdx.x;
    if (c < 128) {
        double m = stats[c] / (double)n;
        double var = stats[128 + c] / (double)n - m * m;
        float rs = rsqrtf((float)var + 1e-5f);
        float sc = g[c] * rs;
        scale[c] = sc;
        shift[c] = be[c] - (float)m * sc;
    }
}

// prob = sigmoid( relu(M2*scale+shift) @ Wm3 + bm3 )
__global__ void gemv_prob(const __hip_bfloat16* __restrict__ M2,
                          const float* __restrict__ scale, const float* __restrict__ shift,
                          const float* __restrict__ Wm3, const float* __restrict__ bm3,
                          float* __restrict__ outp, int n) {
    int wid = (int)((blockIdx.x * (size_t)blockDim.x + threadIdx.x) >> 6);
    int lane = threadIdx.x & 63;
    if (wid >= n) return;
    float s = 0.f;
#pragma unroll
    for (int t = 0; t < 2; ++t) {
        int k = lane + t * 64;
        float a = __bfloat162float(M2[(size_t)wid * 128 + k]);
        a = fmaxf(a * scale[k] + shift[k], 0.f);
        s += a * Wm3[k];
    }
#pragma unroll
    for (int off = 32; off > 0; off >>= 1) s += __shfl_down(s, off);
    if (lane == 0) outp[wid] = 1.f / (1.f + __expf(-(s + bm3[0])));
}

extern "C" void kernel_launch(void* const* d_in, const int* in_sizes, int n_in,
                              void* d_out, int out_size, void* d_ws, size_t ws_size,
                              hipStream_t stream) {
    const float* x   = (const float*)d_in[0];
    const int*   pos = (const int*)d_in[1];
    const int*   neg = (const int*)d_in[2];
    const float* W_in = (const float*)d_in[3];
    const float* b_in = (const float*)d_in[4];
    const float* W1p = (const float*)d_in[5];
    const float* b1p = (const float*)d_in[6];
    const float* W1n = (const float*)d_in[7];
    const float* b1n = (const float*)d_in[8];
    const float* W2p = (const float*)d_in[9];
    const float* b2p = (const float*)d_in[10];
    const float* W2n = (const float*)d_in[11];
    const float* b2n = (const float*)d_in[12];
    const float* Wz  = (const float*)d_in[13];
    const float* bz  = (const float*)d_in[14];
    const float* Wm1 = (const float*)d_in[15];
    const float* bm1 = (const float*)d_in[16];
    const float* g1  = (const float*)d_in[17];
    const float* be1 = (const float*)d_in[18];
    const float* Wm2 = (const float*)d_in[19];
    const float* bm2 = (const float*)d_in[20];
    const float* g2  = (const float*)d_in[21];
    const float* be2 = (const float*)d_in[22];
    const float* Wm3 = (const float*)d_in[23];
    const float* bm3 = (const float*)d_in[24];

    char* ws = (char*)d_ws;
    size_t off = 0;
    auto carve = [&](size_t bytes) -> void* {
        void* p = (void*)(ws + off);
        off = (off + bytes + 255) & ~(size_t)255;
        return p;
    };
    const size_t NB  = (size_t)NN * 128 * sizeof(float);
    const size_t NBH = (size_t)NN * 128 * sizeof(__hip_bfloat16);
    float* slot1 = (float*)carve(NB);                     // aggC f32; later aliased by P/Q bf16
    __hip_bfloat16* slotA = (__hip_bfloat16*)carve(NBH);  // hB -> m1B
    __hip_bfloat16* slotB = (__hip_bfloat16*)carve(NBH);  // u1B -> z2B -> m2B
    __hip_bfloat16* slotC = (__hip_bfloat16*)carve(NBH);  // z1B -> zB
    int* cnt_p = (int*)carve(NN * sizeof(int));
    int* cnt_n = (int*)carve(NN * sizeof(int));
    int* off_p = (int*)carve(NN * sizeof(int));
    int* off_n = (int*)carve(NN * sizeof(int));
    int* cur_p = (int*)carve(NN * sizeof(int));
    int* cur_n = (int*)carve(NN * sizeof(int));
    int* csr_p = (int*)carve(EP * sizeof(int));
    int* csr_n = (int*)carve(EN * sizeof(int));
    int* bsum_p = (int*)carve(1024 * sizeof(int));
    int* bsum_n = (int*)carve(1024 * sizeof(int));
    __hip_bfloat16* WtIn = (__hip_bfloat16*)carve(128 * 64 * 2);
    __hip_bfloat16* WtC1 = (__hip_bfloat16*)carve(128 * 128 * 2);
    __hip_bfloat16* WtL1 = (__hip_bfloat16*)carve(128 * 128 * 2);
    __hip_bfloat16* Wt2  = (__hip_bfloat16*)carve(128 * 384 * 2);
    __hip_bfloat16* WtZ  = (__hip_bfloat16*)carve(128 * 128 * 2);
    __hip_bfloat16* WtM1 = (__hip_bfloat16*)carve(128 * 128 * 2);
    __hip_bfloat16* WtM2 = (__hip_bfloat16*)carve(128 * 128 * 2);
    float* bcat1 = (float*)carve(128 * sizeof(float));
    float* b2cat = (float*)carve(128 * sizeof(float));
    double* stats1 = (double*)carve(256 * sizeof(double));
    double* stats2 = (double*)carve(256 * sizeof(double));
    float* scale1 = (float*)carve(128 * sizeof(float));
    float* shift1 = (float*)carve(128 * sizeof(float));
    float* scale2 = (float*)carve(128 * sizeof(float));
    float* shift2 = (float*)carve(128 * sizeof(float));
    (void)ws_size; (void)in_sizes; (void)n_in; (void)out_size;

    __hip_bfloat16* aggPb = (__hip_bfloat16*)slot1;       // alias: aggC dead after G3
    __hip_bfloat16* aggQb = aggPb + (size_t)NN * 128;

    float* zout = (float*)d_out;                 // N x 128 (fp32)
    float* pout = zout + (size_t)NN * 128;       // N

    const int TILES = (NN + 127) / 128;          // 1172
    const int GB2 = TILES / 2;                   // 586 (TILES is even)
    const int NBLK = (NN + SCAN_BS - 1) / SCAN_BS;

    // ---- CSR build + weight prep ----
    hipMemsetAsync(cnt_p, 0, NN * sizeof(int), stream);
    hipMemsetAsync(cnt_n, 0, NN * sizeof(int), stream);
    hipMemsetAsync(stats1, 0, 256 * sizeof(double), stream);
    hipMemsetAsync(stats2, 0, 256 * sizeof(double), stream);
    count_kernel<<<(EP + 255) / 256, 256, 0, stream>>>(pos + EP, EP, cnt_p);
    count_kernel<<<(EN + 255) / 256, 256, 0, stream>>>(neg + EN, EN, cnt_n);
    scan_block<<<NBLK, SCAN_BS, 0, stream>>>(cnt_p, NN, off_p, bsum_p);
    scan_block<<<NBLK, SCAN_BS, 0, stream>>>(cnt_n, NN, off_n, bsum_n);
    scan_bsum<<<1, SCAN_BS, 0, stream>>>(bsum_p, NBLK);
    scan_bsum<<<1, SCAN_BS, 0, stream>>>(bsum_n, NBLK);
    scan_add<<<NBLK, SCAN_BS, 0, stream>>>(bsum_p, NN, off_p, cur_p);
    scan_add<<<NBLK, SCAN_BS, 0, stream>>>(bsum_n, NN, off_n, cur_n);
    fill_csr<<<(EP + 255) / 256, 256, 0, stream>>>(pos, pos + EP, EP, cur_p, csr_p);
    fill_csr<<<(EN + 255) / 256, 256, 0, stream>>>(neg, neg + EN, EN, cur_n, csr_n);
    prep_weights<<<192, 256, 0, stream>>>(W_in, W1p, b1p, W1n, b1n, W2p, b2p, W2n, b2n,
                                          Wz, Wm1, Wm2,
                                          WtIn, WtC1, WtL1, Wt2, WtZ, WtM1, WtM2,
                                          bcat1, b2cat);

    // G1: h = x @ WtIn + b_in -> hB (slotA)          [K=64, A f32]
    sgemm<64, 1, 2, true, true, false, false, false, false, false, true><<<GB2, 256, 0, stream>>>(
        x, nullptr, nullptr, WtIn, b_in, nullptr, nullptr, nullptr, nullptr,
        nullptr, slotA, NN);

    // G2: U1 = h @ WtC1 -> u1B (slotB)
    sgemm<128, 1, 2, false, false, false, false, false, false, false, true><<<GB2, 256, 0, stream>>>(
        slotA, nullptr, nullptr, WtC1, nullptr, nullptr, nullptr, nullptr, nullptr,
        nullptr, slotB, NN);

    // aggC = [mean_pos(U1[:, :64]) | mean_neg(U1[:, 64:])] -> slot1 (f32)
    gather1v<<<(NN * 16 + 255) / 256, 256, 0, stream>>>(
        slotB, off_p, cnt_p, csr_p, off_n, cnt_n, csr_n, slot1);

    // G3: z1 = tanh(aggC + h @ WtL1 + bcat1) -> z1B (slotC)
    sgemm<128, 1, 2, false, true, true, true, false, false, false, true><<<GB2, 256, 0, stream>>>(
        slotA, nullptr, nullptr, WtL1, bcat1, slot1, nullptr, nullptr, nullptr,
        nullptr, slotC, NN);

    // P = mean_pos(z1), Q = mean_neg(z1) -> bf16, alias slot1
    gather2v<<<(NN * 32 + 255) / 256, 256, 0, stream>>>(
        slotC, off_p, cnt_p, csr_p, off_n, cnt_n, csr_n, aggPb, aggQb);

    // G4: z2 = tanh([P|Q|z1] @ Wt2 + b2cat) -> z2B (slotB, u1 dead)   [K=384, TPB=1]
    sgemm<384, 3, 1, false, true, true, false, false, false, false, true><<<TILES, 256, 0, stream>>>(
        aggPb, aggQb, slotC, Wt2, b2cat, nullptr, nullptr, nullptr, nullptr,
        nullptr, slotB, NN);

    // G5: z = tanh(z2 @ WtZ + bz) -> zout (f32, d_out) + zB (slotC, z1 dead)
    sgemm<128, 1, 2, false, true, true, false, false, false, true, true><<<GB2, 256, 0, stream>>>(
        slotB, nullptr, nullptr, WtZ, bz, nullptr, nullptr, nullptr, nullptr,
        zout, slotC, NN);

    // G6: M1 = zB @ WtM1 + bm1 -> m1B (slotA, h dead) + stats1
    sgemm<128, 1, 2, false, true, false, false, false, true, false, true><<<GB2, 256, 0, stream>>>(
        slotC, nullptr, nullptr, WtM1, bm1, nullptr, nullptr, nullptr, stats1,
        nullptr, slotA, NN);
    bn_finalize<<<1, 128, 0, stream>>>(stats1, g1, be1, scale1, shift1, NN);

    // G7: M2 = relu(BN(M1)) @ WtM2 + bm2 -> m2B (slotB, z2 dead) + stats2
    sgemm<128, 1, 2, false, true, false, false, true, true, false, true><<<GB2, 256, 0, stream>>>(
        slotA, nullptr, nullptr, WtM2, bm2, nullptr, scale1, shift1, stats2,
        nullptr, slotB, NN);
    bn_finalize<<<1, 128, 0, stream>>>(stats2, g2, be2, scale2, shift2, NN);

    // prob = sigmoid(relu(BN(M2)) @ Wm3 + bm3) -> d_out tail
    gemv_prob<<<(NN + 3) / 4, 256, 0, stream>>>(slotB, scale2, shift2, Wm3, bm3, pout, NN);
}

// Round 10
// 569.920 us; speedup vs baseline: 1.3959x; 1.3959x over previous
//
#include <hip/hip_runtime.h>
#include <hip/hip_bf16.h>
#include <cstddef>
#include <cstdint>

#define NN 150000
#define EP 400000
#define EN 200000
#define SCAN_BS 256

typedef __bf16 bf16x8 __attribute__((ext_vector_type(8)));
typedef float  f32x4  __attribute__((ext_vector_type(4)));

__device__ __forceinline__ float fast_tanh(float x) {
    float e = __expf(2.f * x);
    return 1.f - 2.f / (e + 1.f);
}

// async global->LDS 16B copy (no VGPR round trip; tracked by vmcnt)
__device__ __forceinline__ void async16(const void* g, void* l) {
    __builtin_amdgcn_global_load_lds(
        (const __attribute__((address_space(1))) void*)g,
        (__attribute__((address_space(3))) void*)l, 16, 0, 0);
}

// ---------------- counts ----------------
__global__ void count_kernel(const int* __restrict__ dst, int E, int* __restrict__ cnt) {
    int e = blockIdx.x * blockDim.x + threadIdx.x;
    if (e < E) atomicAdd(&cnt[dst[e]], 1);
}

// ---------------- exclusive scan (3-kernel) ----------------
__global__ void scan_block(const int* __restrict__ cnt, int n,
                           int* __restrict__ excl, int* __restrict__ bsum) {
    __shared__ int lds[SCAN_BS];
    int tid = threadIdx.x;
    int i = blockIdx.x * SCAN_BS + tid;
    int v = (i < n) ? cnt[i] : 0;
    lds[tid] = v;
    __syncthreads();
    for (int d = 1; d < SCAN_BS; d <<= 1) {
        int t = (tid >= d) ? lds[tid - d] : 0;
        __syncthreads();
        lds[tid] += t;
        __syncthreads();
    }
    if (i < n) excl[i] = lds[tid] - v;
    if (tid == SCAN_BS - 1) bsum[blockIdx.x] = lds[tid];
}

__global__ void scan_bsum(int* __restrict__ bsum, int nb) {
    __shared__ int lds[SCAN_BS];
    __shared__ int carry;
    int tid = threadIdx.x;
    if (tid == 0) carry = 0;
    __syncthreads();
    for (int base = 0; base < nb; base += SCAN_BS) {
        int i = base + tid;
        int v = (i < nb) ? bsum[i] : 0;
        lds[tid] = v;
        __syncthreads();
        for (int d = 1; d < SCAN_BS; d <<= 1) {
            int t = (tid >= d) ? lds[tid - d] : 0;
            __syncthreads();
            lds[tid] += t;
            __syncthreads();
        }
        if (i < nb) bsum[i] = lds[tid] - v + carry;
        __syncthreads();
        if (tid == 0) carry += lds[SCAN_BS - 1];
        __syncthreads();
    }
}

__global__ void scan_add(const int* __restrict__ bsum, int n,
                         int* __restrict__ excl, int* __restrict__ cur) {
    int i = blockIdx.x * SCAN_BS + threadIdx.x;
    if (i < n) {
        int o = excl[i] + bsum[blockIdx.x];
        excl[i] = o;
        cur[i] = o;
    }
}

__global__ void fill_csr(const int* __restrict__ src, const int* __restrict__ dst, int E,
                         int* __restrict__ cur, int* __restrict__ csr) {
    int e = blockIdx.x * blockDim.x + threadIdx.x;
    if (e < E) {
        int d = dst[e];
        int p = atomicAdd(&cur[d], 1);
        csr[p] = src[e];
    }
}

// ---------------- vectorized CSR gather means (bf16x8 per lane) ----------------
__global__ void gather1v(const __hip_bfloat16* __restrict__ U1,
                         const int* __restrict__ offp, const int* __restrict__ cntp,
                         const int* __restrict__ csrp,
                         const int* __restrict__ offn, const int* __restrict__ cntn,
                         const int* __restrict__ csrn,
                         float* __restrict__ out) {
    int gid = blockIdx.x * blockDim.x + threadIdx.x;
    if (gid >= NN * 16) return;
    int d = gid >> 4, cg = gid & 15;
    int c0 = cg * 8;
    const int* off; const int* cnt; const int* csr;
    if (cg < 8) { off = offp; cnt = cntp; csr = csrp; }
    else        { off = offn; cnt = cntn; csr = csrn; }
    int o = off[d], dg = cnt[d];
    float acc[8] = {0.f, 0.f, 0.f, 0.f, 0.f, 0.f, 0.f, 0.f};
    for (int e = 0; e < dg; ++e) {
        int s = csr[o + e];
        bf16x8 v = *reinterpret_cast<const bf16x8*>(&U1[(size_t)s * 128 + c0]);
#pragma unroll
        for (int j = 0; j < 8; ++j) acc[j] += (float)v[j];
    }
    float inv = 1.f / (float)(dg > 0 ? dg : 1);
    float4 o0 = make_float4(acc[0] * inv, acc[1] * inv, acc[2] * inv, acc[3] * inv);
    float4 o1 = make_float4(acc[4] * inv, acc[5] * inv, acc[6] * inv, acc[7] * inv);
    *reinterpret_cast<float4*>(&out[(size_t)d * 128 + c0 + 0]) = o0;
    *reinterpret_cast<float4*>(&out[(size_t)d * 128 + c0 + 4]) = o1;
}

__global__ void gather2v(const __hip_bfloat16* __restrict__ z1,
                         const int* __restrict__ offp, const int* __restrict__ cntp,
                         const int* __restrict__ csrp,
                         const int* __restrict__ offn, const int* __restrict__ cntn,
                         const int* __restrict__ csrn,
                         __hip_bfloat16* __restrict__ P, __hip_bfloat16* __restrict__ Q) {
    int gid = blockIdx.x * blockDim.x + threadIdx.x;
    if (gid >= NN * 32) return;
    int d = gid >> 5, cg = gid & 31;
    const int* off; const int* cnt; const int* csr; __hip_bfloat16* out; int c0;
    if (cg < 16) { off = offp; cnt = cntp; csr = csrp; out = P; c0 = cg * 8; }
    else         { off = offn; cnt = cntn; csr = csrn; out = Q; c0 = (cg - 16) * 8; }
    int o = off[d], dg = cnt[d];
    float acc[8] = {0.f, 0.f, 0.f, 0.f, 0.f, 0.f, 0.f, 0.f};
    for (int e = 0; e < dg; ++e) {
        int s = csr[o + e];
        bf16x8 v = *reinterpret_cast<const bf16x8*>(&z1[(size_t)s * 128 + c0]);
#pragma unroll
        for (int j = 0; j < 8; ++j) acc[j] += (float)v[j];
    }
    float inv = 1.f / (float)(dg > 0 ? dg : 1);
    bf16x8 r;
#pragma unroll
    for (int j = 0; j < 8; ++j) r[j] = (__bf16)(acc[j] * inv);
    *reinterpret_cast<bf16x8*>(&out[(size_t)d * 128 + c0]) = r;
}

// ---------------- weight prep ----------------
__global__ void prep_weights(const float* __restrict__ W_in,
                             const float* __restrict__ W1p, const float* __restrict__ b1p,
                             const float* __restrict__ W1n, const float* __restrict__ b1n,
                             const float* __restrict__ W2p, const float* __restrict__ b2p,
                             const float* __restrict__ W2n, const float* __restrict__ b2n,
                             const float* __restrict__ Wz,  const float* __restrict__ Wm1,
                             const float* __restrict__ Wm2,
                             __hip_bfloat16* __restrict__ WtIn,  // [128][64]
                             __hip_bfloat16* __restrict__ WtC1,  // [128][128]
                             __hip_bfloat16* __restrict__ WtL1,  // [128][128]
                             __hip_bfloat16* __restrict__ Wt2,   // [128][384]
                             __hip_bfloat16* __restrict__ WtZ,
                             __hip_bfloat16* __restrict__ WtM1,
                             __hip_bfloat16* __restrict__ WtM2,
                             float* __restrict__ bcat1, float* __restrict__ b2cat) {
    int idx = blockIdx.x * blockDim.x + threadIdx.x;
    if (idx < 128 * 64) {
        int c = idx >> 6, k = idx & 63;
        WtIn[idx] = __float2bfloat16(W_in[k * 128 + c]);
    }
    if (idx < 128 * 128) {
        int c = idx >> 7, k = idx & 127;
        float v1 = (c < 64) ? W1p[k * 64 + c] : W1n[k * 64 + (c - 64)];
        WtC1[idx] = __float2bfloat16(v1);
        float v2 = (c < 64) ? W1p[(128 + k) * 64 + c] : W1n[(128 + k) * 64 + (c - 64)];
        WtL1[idx] = __float2bfloat16(v2);
        WtZ[idx]  = __float2bfloat16(Wz[k * 128 + c]);
        WtM1[idx] = __float2bfloat16(Wm1[k * 128 + c]);
        WtM2[idx] = __float2bfloat16(Wm2[k * 128 + c]);
    }
    if (idx < 128 * 384) {
        int c = idx / 384, r = idx % 384;
        float v = 0.f;
        if (r < 64)       { if (c < 64)  v = W2p[r * 64 + c]; }
        else if (r < 128) { if (c >= 64) v = W2n[(r - 64) * 64 + (c - 64)]; }
        else if (r < 192) { if (c >= 64) v = W2n[(64 + r - 128) * 64 + (c - 64)]; }
        else if (r < 256) { if (c < 64)  v = W2p[(64 + r - 192) * 64 + c]; }
        else if (r < 320) { if (c < 64)  v = W2p[(128 + r - 256) * 64 + c]; }
        else              { if (c >= 64) v = W2n[(128 + r - 320) * 64 + (c - 64)]; }
        Wt2[idx] = __float2bfloat16(v);
    }
    if (idx < 128) {
        bcat1[idx] = (idx < 64) ? b1p[idx] : b1n[idx - 64];
        b2cat[idx] = (idx < 64) ? b2p[idx] : b2n[idx - 64];
    }
}

// ============ all-async LDS-staged MFMA GEMM: 32 rows/wave, 128 rows/block ============
// BOTH W and A staged via global_load_lds in fragment order (zero destination VGPRs,
// all 16 async ops in flight per thread, one barrier drains everything).
// W slot  = (c*NFC + kk)*64 + lane          (8*NFC*64 slots)
// A slot  = ((wid*2 + t)*NFC + kk)*64 + lane (8*NFC*64 slots)
// Both read back as contiguous ds_read_b128 (conflict-free by construction).
// A-row clamp applied on the per-lane GLOBAL source address.
template<int K, int NSEG, bool AF32, bool BIAS, bool TANH_ACT, bool ADDEND,
         bool BNIN, bool STATS, bool STOREF, bool STOREB>
__global__ __launch_bounds__(256, 2) void sgemm(
    const void* __restrict__ A0, const void* __restrict__ A1, const void* __restrict__ A2,
    const __hip_bfloat16* __restrict__ Wt,   // [128][K]
    const float* __restrict__ bias,
    const float* __restrict__ addend,        // n x 128 f32
    const float* __restrict__ scale, const float* __restrict__ shift,
    double* __restrict__ stats,
    float* __restrict__ outf, __hip_bfloat16* __restrict__ outb, int n)
{
    constexpr int CHUNK = (K < 128) ? K : 128;
    constexpr int NCH = K / CHUNK;
    constexpr int NFC = CHUNK / 32;          // frags per chunk per row-tile (2 or 4)
    constexpr int SEGW = K / NSEG;
    constexpr int WSLOT = 8 * NFC * 64;      // W 16B fragment slots
    constexpr int ASLOT = AF32 ? 0 : 8 * NFC * 64;
    __shared__ __align__(16) char wlds[WSLOT * 16];
    __shared__ __align__(16) char alds[(ASLOT ? ASLOT : 1) * 16];
    __shared__ float ssum[128], ssq[128];
    const int tid = threadIdx.x, lane = tid & 63, wid = tid >> 6;
    const int l16 = lane & 15, lhi = lane >> 4;
    const int tile = blockIdx.x;
    const int brow = tile * 128 + wid * 32;

    if (STATS) {
        if (tid < 128) { ssum[tid] = 0.f; ssq[tid] = 0.f; }
    }

    f32x4 acc[2][8];
#pragma unroll
    for (int t = 0; t < 2; ++t)
#pragma unroll
        for (int c = 0; c < 8; ++c)
#pragma unroll
            for (int i = 0; i < 4; ++i) acc[t][c][i] = 0.f;

    bf16x8 a32[2][2];   // AF32 path register fragments (K=64 only)

#pragma unroll
    for (int ch = 0; ch < NCH; ++ch) {
        // ---- async-stage W chunk (fragment order) ----
#pragma unroll
        for (int i = 0; i < WSLOT / 256; ++i) {
            int slot = tid + i * 256;
            int ln = slot & 63, f = slot >> 6;
            int c = f / NFC, kk = f % NFC;
            int row = c * 16 + (ln & 15);
            int gk = ch * CHUNK + kk * 32 + (ln >> 4) * 8;
            async16(Wt + (size_t)row * K + gk, wlds + slot * 16);
        }
        if (AF32) {
            // G1 only: A is f32, load to regs and convert (K=64)
#pragma unroll
            for (int kk = 0; kk < NFC; ++kk)
#pragma unroll
                for (int t = 0; t < 2; ++t) {
                    int row = brow + t * 16 + l16; if (row > n - 1) row = n - 1;
                    const float* p = (const float*)A0 + (size_t)row * SEGW + kk * 32 + lhi * 8;
                    float4 u0 = *reinterpret_cast<const float4*>(p);
                    float4 u1 = *reinterpret_cast<const float4*>(p + 4);
                    bf16x8 a;
                    a[0] = (__bf16)u0.x; a[1] = (__bf16)u0.y; a[2] = (__bf16)u0.z; a[3] = (__bf16)u0.w;
                    a[4] = (__bf16)u1.x; a[5] = (__bf16)u1.y; a[6] = (__bf16)u1.z; a[7] = (__bf16)u1.w;
                    a32[kk][t] = a;
                }
        } else {
            // ---- async-stage A chunk (fragment order, per-lane clamped source) ----
            const __hip_bfloat16* Aseg = (const __hip_bfloat16*)
                ((NSEG == 1) ? A0 : (ch == 0 ? A0 : (ch == 1 ? A1 : A2)));
            const int kbase = (NSEG == 1) ? ch * CHUNK : 0;
#pragma unroll
            for (int i = 0; i < (ASLOT ? ASLOT / 256 : 0); ++i) {
                int slot = tid + i * 256;
                int ln = slot & 63, f = slot >> 6;      // (w*2+t)*NFC + kk
                int w = f / (2 * NFC);
                int rem = f % (2 * NFC);
                int t = rem / NFC, kk = rem % NFC;
                int row = tile * 128 + w * 32 + t * 16 + (ln & 15);
                if (row > n - 1) row = n - 1;
                async16(Aseg + (size_t)row * SEGW + kbase + kk * 32 + (ln >> 4) * 8,
                        alds + slot * 16);
            }
        }
        __syncthreads();   // drains all async staging (vmcnt) + reg loads

        // ---- MFMA from LDS ----
#pragma unroll
        for (int kk = 0; kk < NFC; ++kk) {
            bf16x8 af[2];
#pragma unroll
            for (int t = 0; t < 2; ++t) {
                if (AF32) {
                    af[t] = a32[kk][t];
                } else {
                    bf16x8 a = *reinterpret_cast<const bf16x8*>(
                        alds + ((((wid * 2 + t) * NFC + kk) * 64 + lane) << 4));
                    if (BNIN) {
#pragma unroll
                        for (int j = 0; j < 8; ++j) {
                            int k = kk * 32 + lhi * 8 + j;
                            a[j] = (__bf16)fmaxf((float)a[j] * scale[k] + shift[k], 0.f);
                        }
                    }
                    af[t] = a;
                }
            }
#pragma unroll
            for (int c = 0; c < 8; ++c) {
                bf16x8 b = *reinterpret_cast<const bf16x8*>(
                    wlds + (((c * NFC + kk) * 64 + lane) << 4));
                acc[0][c] = __builtin_amdgcn_mfma_f32_16x16x32_bf16(af[0], b, acc[0][c], 0, 0, 0);
                acc[1][c] = __builtin_amdgcn_mfma_f32_16x16x32_bf16(af[1], b, acc[1][c], 0, 0, 0);
            }
        }
        if (NCH > 1 && ch != NCH - 1) __syncthreads();   // LDS reads done before restage
    }

    // ---- epilogue ----
#pragma unroll
    for (int t = 0; t < 2; ++t)
#pragma unroll
        for (int c = 0; c < 8; ++c) {
            const int col = c * 16 + l16;
            const float bv = BIAS ? bias[col] : 0.f;
            float s = 0.f, q = 0.f;
#pragma unroll
            for (int r = 0; r < 4; ++r) {
                int grow = brow + t * 16 + lhi * 4 + r;
                bool ok = grow < n;
                float v = acc[t][c][r] + bv;
                if (ADDEND) { if (ok) v += addend[(size_t)grow * 128 + col]; }
                if (TANH_ACT) v = fast_tanh(v);
                if (ok) {
                    if (STOREF) outf[(size_t)grow * 128 + col] = v;
                    if (STOREB) outb[(size_t)grow * 128 + col] = __float2bfloat16(v);
                    if (STATS) { s += v; q += v * v; }
                }
            }
            if (STATS) { atomicAdd(&ssum[col], s); atomicAdd(&ssq[col], q); }
        }
    if (STATS) {
        __syncthreads();
        if (tid < 128) {
            atomicAdd(&stats[tid],       (double)ssum[tid]);
            atomicAdd(&stats[128 + tid], (double)ssq[tid]);
        }
    }
}

// BN finalize -> scale/shift form: relu(a*scale + shift)
__global__ void bn_finalize(const double* __restrict__ stats,
                            const float* __restrict__ g, const float* __restrict__ be,
                            float* __restrict__ scale, float* __restrict__ shift, int n) {
    int c = threadIdx.x;
    if (c < 128) {
        double m = stats[c] / (double)n;
        double var = stats[128 + c] / (double)n - m * m;
        float rs = rsqrtf((float)var + 1e-5f);
        float sc = g[c] * rs;
        scale[c] = sc;
        shift[c] = be[c] - (float)m * sc;
    }
}

// prob = sigmoid( relu(M2*scale+shift) @ Wm3 + bm3 )
__global__ void gemv_prob(const __hip_bfloat16* __restrict__ M2,
                          const float* __restrict__ scale, const float* __restrict__ shift,
                          const float* __restrict__ Wm3, const float* __restrict__ bm3,
                          float* __restrict__ outp, int n) {
    int wid = (int)((blockIdx.x * (size_t)blockDim.x + threadIdx.x) >> 6);
    int lane = threadIdx.x & 63;
    if (wid >= n) return;
    float s = 0.f;
#pragma unroll
    for (int t = 0; t < 2; ++t) {
        int k = lane + t * 64;
        float a = __bfloat162float(M2[(size_t)wid * 128 + k]);
        a = fmaxf(a * scale[k] + shift[k], 0.f);
        s += a * Wm3[k];
    }
#pragma unroll
    for (int off = 32; off > 0; off >>= 1) s += __shfl_down(s, off);
    if (lane == 0) outp[wid] = 1.f / (1.f + __expf(-(s + bm3[0])));
}

extern "C" void kernel_launch(void* const* d_in, const int* in_sizes, int n_in,
                              void* d_out, int out_size, void* d_ws, size_t ws_size,
                              hipStream_t stream) {
    const float* x   = (const float*)d_in[0];
    const int*   pos = (const int*)d_in[1];
    const int*   neg = (const int*)d_in[2];
    const float* W_in = (const float*)d_in[3];
    const float* b_in = (const float*)d_in[4];
    const float* W1p = (const float*)d_in[5];
    const float* b1p = (const float*)d_in[6];
    const float* W1n = (const float*)d_in[7];
    const float* b1n = (const float*)d_in[8];
    const float* W2p = (const float*)d_in[9];
    const float* b2p = (const float*)d_in[10];
    const float* W2n = (const float*)d_in[11];
    const float* b2n = (const float*)d_in[12];
    const float* Wz  = (const float*)d_in[13];
    const float* bz  = (const float*)d_in[14];
    const float* Wm1 = (const float*)d_in[15];
    const float* bm1 = (const float*)d_in[16];
    const float* g1  = (const float*)d_in[17];
    const float* be1 = (const float*)d_in[18];
    const float* Wm2 = (const float*)d_in[19];
    const float* bm2 = (const float*)d_in[20];
    const float* g2  = (const float*)d_in[21];
    const float* be2 = (const float*)d_in[22];
    const float* Wm3 = (const float*)d_in[23];
    const float* bm3 = (const float*)d_in[24];

    char* ws = (char*)d_ws;
    size_t off = 0;
    auto carve = [&](size_t bytes) -> void* {
        void* p = (void*)(ws + off);
        off = (off + bytes + 255) & ~(size_t)255;
        return p;
    };
    const size_t NB  = (size_t)NN * 128 * sizeof(float);
    const size_t NBH = (size_t)NN * 128 * sizeof(__hip_bfloat16);
    float* slot1 = (float*)carve(NB);                     // aggC f32; later aliased by P/Q bf16
    __hip_bfloat16* slotA = (__hip_bfloat16*)carve(NBH);  // hB -> m1B
    __hip_bfloat16* slotB = (__hip_bfloat16*)carve(NBH);  // u1B -> z2B -> m2B
    __hip_bfloat16* slotC = (__hip_bfloat16*)carve(NBH);  // z1B -> zB
    int* cnt_p = (int*)carve(NN * sizeof(int));
    int* cnt_n = (int*)carve(NN * sizeof(int));
    int* off_p = (int*)carve(NN * sizeof(int));
    int* off_n = (int*)carve(NN * sizeof(int));
    int* cur_p = (int*)carve(NN * sizeof(int));
    int* cur_n = (int*)carve(NN * sizeof(int));
    int* csr_p = (int*)carve(EP * sizeof(int));
    int* csr_n = (int*)carve(EN * sizeof(int));
    int* bsum_p = (int*)carve(1024 * sizeof(int));
    int* bsum_n = (int*)carve(1024 * sizeof(int));
    __hip_bfloat16* WtIn = (__hip_bfloat16*)carve(128 * 64 * 2);
    __hip_bfloat16* WtC1 = (__hip_bfloat16*)carve(128 * 128 * 2);
    __hip_bfloat16* WtL1 = (__hip_bfloat16*)carve(128 * 128 * 2);
    __hip_bfloat16* Wt2  = (__hip_bfloat16*)carve(128 * 384 * 2);
    __hip_bfloat16* WtZ  = (__hip_bfloat16*)carve(128 * 128 * 2);
    __hip_bfloat16* WtM1 = (__hip_bfloat16*)carve(128 * 128 * 2);
    __hip_bfloat16* WtM2 = (__hip_bfloat16*)carve(128 * 128 * 2);
    float* bcat1 = (float*)carve(128 * sizeof(float));
    float* b2cat = (float*)carve(128 * sizeof(float));
    double* stats1 = (double*)carve(256 * sizeof(double));
    double* stats2 = (double*)carve(256 * sizeof(double));
    float* scale1 = (float*)carve(128 * sizeof(float));
    float* shift1 = (float*)carve(128 * sizeof(float));
    float* scale2 = (float*)carve(128 * sizeof(float));
    float* shift2 = (float*)carve(128 * sizeof(float));
    (void)ws_size; (void)in_sizes; (void)n_in; (void)out_size;

    __hip_bfloat16* aggPb = (__hip_bfloat16*)slot1;       // alias: aggC dead after G3
    __hip_bfloat16* aggQb = aggPb + (size_t)NN * 128;

    float* zout = (float*)d_out;                 // N x 128 (fp32)
    float* pout = zout + (size_t)NN * 128;       // N

    const int TILES = (NN + 127) / 128;          // 1172
    const int NBLK = (NN + SCAN_BS - 1) / SCAN_BS;

    // ---- CSR build + weight prep ----
    hipMemsetAsync(cnt_p, 0, NN * sizeof(int), stream);
    hipMemsetAsync(cnt_n, 0, NN * sizeof(int), stream);
    hipMemsetAsync(stats1, 0, 256 * sizeof(double), stream);
    hipMemsetAsync(stats2, 0, 256 * sizeof(double), stream);
    count_kernel<<<(EP + 255) / 256, 256, 0, stream>>>(pos + EP, EP, cnt_p);
    count_kernel<<<(EN + 255) / 256, 256, 0, stream>>>(neg + EN, EN, cnt_n);
    scan_block<<<NBLK, SCAN_BS, 0, stream>>>(cnt_p, NN, off_p, bsum_p);
    scan_block<<<NBLK, SCAN_BS, 0, stream>>>(cnt_n, NN, off_n, bsum_n);
    scan_bsum<<<1, SCAN_BS, 0, stream>>>(bsum_p, NBLK);
    scan_bsum<<<1, SCAN_BS, 0, stream>>>(bsum_n, NBLK);
    scan_add<<<NBLK, SCAN_BS, 0, stream>>>(bsum_p, NN, off_p, cur_p);
    scan_add<<<NBLK, SCAN_BS, 0, stream>>>(bsum_n, NN, off_n, cur_n);
    fill_csr<<<(EP + 255) / 256, 256, 0, stream>>>(pos, pos + EP, EP, cur_p, csr_p);
    fill_csr<<<(EN + 255) / 256, 256, 0, stream>>>(neg, neg + EN, EN, cur_n, csr_n);
    prep_weights<<<192, 256, 0, stream>>>(W_in, W1p, b1p, W1n, b1n, W2p, b2p, W2n, b2n,
                                          Wz, Wm1, Wm2,
                                          WtIn, WtC1, WtL1, Wt2, WtZ, WtM1, WtM2,
                                          bcat1, b2cat);

    // G1: h = x @ WtIn + b_in -> hB (slotA)          [K=64, A f32 reg path]
    sgemm<64, 1, true, true, false, false, false, false, false, true><<<TILES, 256, 0, stream>>>(
        x, nullptr, nullptr, WtIn, b_in, nullptr, nullptr, nullptr, nullptr,
        nullptr, slotA, NN);

    // G2: U1 = h @ WtC1 -> u1B (slotB)
    sgemm<128, 1, false, false, false, false, false, false, false, true><<<TILES, 256, 0, stream>>>(
        slotA, nullptr, nullptr, WtC1, nullptr, nullptr, nullptr, nullptr, nullptr,
        nullptr, slotB, NN);

    // aggC = [mean_pos(U1[:, :64]) | mean_neg(U1[:, 64:])] -> slot1 (f32)
    gather1v<<<(NN * 16 + 255) / 256, 256, 0, stream>>>(
        slotB, off_p, cnt_p, csr_p, off_n, cnt_n, csr_n, slot1);

    // G3: z1 = tanh(aggC + h @ WtL1 + bcat1) -> z1B (slotC)
    sgemm<128, 1, false, true, true, true, false, false, false, true><<<TILES, 256, 0, stream>>>(
        slotA, nullptr, nullptr, WtL1, bcat1, slot1, nullptr, nullptr, nullptr,
        nullptr, slotC, NN);

    // P = mean_pos(z1), Q = mean_neg(z1) -> bf16, alias slot1
    gather2v<<<(NN * 32 + 255) / 256, 256, 0, stream>>>(
        slotC, off_p, cnt_p, csr_p, off_n, cnt_n, csr_n, aggPb, aggQb);

    // G4: z2 = tanh([P|Q|z1] @ Wt2 + b2cat) -> z2B (slotB, u1 dead)   [K=384, 3 chunks]
    sgemm<384, 3, false, true, true, false, false, false, false, true><<<TILES, 256, 0, stream>>>(
        aggPb, aggQb, slotC, Wt2, b2cat, nullptr, nullptr, nullptr, nullptr,
        nullptr, slotB, NN);

    // G5: z = tanh(z2 @ WtZ + bz) -> zout (f32, d_out) + zB (slotC, z1 dead)
    sgemm<128, 1, false, true, true, false, false, false, true, true><<<TILES, 256, 0, stream>>>(
        slotB, nullptr, nullptr, WtZ, bz, nullptr, nullptr, nullptr, nullptr,
        zout, slotC, NN);

    // G6: M1 = zB @ WtM1 + bm1 -> m1B (slotA, h dead) + stats1
    sgemm<128, 1, false, true, false, false, false, true, false, true><<<TILES, 256, 0, stream>>>(
        slotC, nullptr, nullptr, WtM1, bm1, nullptr, nullptr, nullptr, stats1,
        nullptr, slotA, NN);
    bn_finalize<<<1, 128, 0, stream>>>(stats1, g1, be1, scale1, shift1, NN);

    // G7: M2 = relu(BN(M1)) @ WtM2 + bm2 -> m2B (slotB, z2 dead) + stats2
    sgemm<128, 1, false, true, false, false, true, true, false, true><<<TILES, 256, 0, stream>>>(
        slotA, nullptr, nullptr, WtM2, bm2, nullptr, scale1, shift1, stats2,
        nullptr, slotB, NN);
    bn_finalize<<<1, 128, 0, stream>>>(stats2, g2, be2, scale2, shift2, NN);

    // prob = sigmoid(relu(BN(M2)) @ Wm3 + bm3) -> d_out tail
    gemv_prob<<<(NN + 3) / 4, 256, 0, stream>>>(slotB, scale2, shift2, Wm3, bm3, pout, NN);
}

// Round 11
// 521.940 us; speedup vs baseline: 1.5243x; 1.0919x over previous
//
#include <hip/hip_runtime.h>
#include <hip/hip_bf16.h>
#include <cstddef>
#include <cstdint>

#define NN 150000
#define EP 400000
#define EN 200000
#define SCAN_BS 256

typedef __bf16 bf16x8 __attribute__((ext_vector_type(8)));
typedef float  f32x4  __attribute__((ext_vector_type(4)));

__device__ __forceinline__ float fast_tanh(float x) {
    float e = __expf(2.f * x);
    return 1.f - 2.f / (e + 1.f);
}

// async global->LDS 16B copy (no VGPR round trip; tracked by vmcnt)
__device__ __forceinline__ void async16(const void* g, void* l) {
    __builtin_amdgcn_global_load_lds(
        (const __attribute__((address_space(1))) void*)g,
        (__attribute__((address_space(3))) void*)l, 16, 0, 0);
}

// ---------------- counts ----------------
__global__ void count_kernel(const int* __restrict__ dst, int E, int* __restrict__ cnt) {
    int e = blockIdx.x * blockDim.x + threadIdx.x;
    if (e < E) atomicAdd(&cnt[dst[e]], 1);
}

// ---------------- exclusive scan (3-kernel) ----------------
__global__ void scan_block(const int* __restrict__ cnt, int n,
                           int* __restrict__ excl, int* __restrict__ bsum) {
    __shared__ int lds[SCAN_BS];
    int tid = threadIdx.x;
    int i = blockIdx.x * SCAN_BS + tid;
    int v = (i < n) ? cnt[i] : 0;
    lds[tid] = v;
    __syncthreads();
    for (int d = 1; d < SCAN_BS; d <<= 1) {
        int t = (tid >= d) ? lds[tid - d] : 0;
        __syncthreads();
        lds[tid] += t;
        __syncthreads();
    }
    if (i < n) excl[i] = lds[tid] - v;
    if (tid == SCAN_BS - 1) bsum[blockIdx.x] = lds[tid];
}

__global__ void scan_bsum(int* __restrict__ bsum, int nb) {
    __shared__ int lds[SCAN_BS];
    __shared__ int carry;
    int tid = threadIdx.x;
    if (tid == 0) carry = 0;
    __syncthreads();
    for (int base = 0; base < nb; base += SCAN_BS) {
        int i = base + tid;
        int v = (i < nb) ? bsum[i] : 0;
        lds[tid] = v;
        __syncthreads();
        for (int d = 1; d < SCAN_BS; d <<= 1) {
            int t = (tid >= d) ? lds[tid - d] : 0;
            __syncthreads();
            lds[tid] += t;
            __syncthreads();
        }
        if (i < nb) bsum[i] = lds[tid] - v + carry;
        __syncthreads();
        if (tid == 0) carry += lds[SCAN_BS - 1];
        __syncthreads();
    }
}

__global__ void scan_add(const int* __restrict__ bsum, int n,
                         int* __restrict__ excl, int* __restrict__ cur) {
    int i = blockIdx.x * SCAN_BS + threadIdx.x;
    if (i < n) {
        int o = excl[i] + bsum[blockIdx.x];
        excl[i] = o;
        cur[i] = o;
    }
}

__global__ void fill_csr(const int* __restrict__ src, const int* __restrict__ dst, int E,
                         int* __restrict__ cur, int* __restrict__ csr) {
    int e = blockIdx.x * blockDim.x + threadIdx.x;
    if (e < E) {
        int d = dst[e];
        int p = atomicAdd(&cur[d], 1);
        csr[p] = src[e];
    }
}

// ---------------- vectorized CSR gather means (bf16x8 per lane) ----------------
__global__ void gather1v(const __hip_bfloat16* __restrict__ U1,
                         const int* __restrict__ offp, const int* __restrict__ cntp,
                         const int* __restrict__ csrp,
                         const int* __restrict__ offn, const int* __restrict__ cntn,
                         const int* __restrict__ csrn,
                         float* __restrict__ out) {
    int gid = blockIdx.x * blockDim.x + threadIdx.x;
    if (gid >= NN * 16) return;
    int d = gid >> 4, cg = gid & 15;
    int c0 = cg * 8;
    const int* off; const int* cnt; const int* csr;
    if (cg < 8) { off = offp; cnt = cntp; csr = csrp; }
    else        { off = offn; cnt = cntn; csr = csrn; }
    int o = off[d], dg = cnt[d];
    float acc[8] = {0.f, 0.f, 0.f, 0.f, 0.f, 0.f, 0.f, 0.f};
    for (int e = 0; e < dg; ++e) {
        int s = csr[o + e];
        bf16x8 v = *reinterpret_cast<const bf16x8*>(&U1[(size_t)s * 128 + c0]);
#pragma unroll
        for (int j = 0; j < 8; ++j) acc[j] += (float)v[j];
    }
    float inv = 1.f / (float)(dg > 0 ? dg : 1);
    float4 o0 = make_float4(acc[0] * inv, acc[1] * inv, acc[2] * inv, acc[3] * inv);
    float4 o1 = make_float4(acc[4] * inv, acc[5] * inv, acc[6] * inv, acc[7] * inv);
    *reinterpret_cast<float4*>(&out[(size_t)d * 128 + c0 + 0]) = o0;
    *reinterpret_cast<float4*>(&out[(size_t)d * 128 + c0 + 4]) = o1;
}

__global__ void gather2v(const __hip_bfloat16* __restrict__ z1,
                         const int* __restrict__ offp, const int* __restrict__ cntp,
                         const int* __restrict__ csrp,
                         const int* __restrict__ offn, const int* __restrict__ cntn,
                         const int* __restrict__ csrn,
                         __hip_bfloat16* __restrict__ P, __hip_bfloat16* __restrict__ Q) {
    int gid = blockIdx.x * blockDim.x + threadIdx.x;
    if (gid >= NN * 32) return;
    int d = gid >> 5, cg = gid & 31;
    const int* off; const int* cnt; const int* csr; __hip_bfloat16* out; int c0;
    if (cg < 16) { off = offp; cnt = cntp; csr = csrp; out = P; c0 = cg * 8; }
    else         { off = offn; cnt = cntn; csr = csrn; out = Q; c0 = (cg - 16) * 8; }
    int o = off[d], dg = cnt[d];
    float acc[8] = {0.f, 0.f, 0.f, 0.f, 0.f, 0.f, 0.f, 0.f};
    for (int e = 0; e < dg; ++e) {
        int s = csr[o + e];
        bf16x8 v = *reinterpret_cast<const bf16x8*>(&z1[(size_t)s * 128 + c0]);
#pragma unroll
        for (int j = 0; j < 8; ++j) acc[j] += (float)v[j];
    }
    float inv = 1.f / (float)(dg > 0 ? dg : 1);
    bf16x8 r;
#pragma unroll
    for (int j = 0; j < 8; ++j) r[j] = (__bf16)(acc[j] * inv);
    *reinterpret_cast<bf16x8*>(&out[(size_t)d * 128 + c0]) = r;
}

// ---------------- weight prep (incl. algebraic fusion of layer-1) ----------------
// Wc1 = W_in @ Wcat1 (64x128), bc1 = b_in @ Wcat1
// Wc2 = W_in @ Wloc1 (64x128), bc2 = b_in @ Wloc1 + bcat1
// (h = x@W_in + b_in has NO activation, so layer 1+2 fold exactly.)
__global__ void prep_weights(const float* __restrict__ W_in, const float* __restrict__ b_in,
                             const float* __restrict__ W1p, const float* __restrict__ b1p,
                             const float* __restrict__ W1n, const float* __restrict__ b1n,
                             const float* __restrict__ W2p, const float* __restrict__ b2p,
                             const float* __restrict__ W2n, const float* __restrict__ b2n,
                             const float* __restrict__ Wz,  const float* __restrict__ Wm1,
                             const float* __restrict__ Wm2,
                             __hip_bfloat16* __restrict__ Wc1t,  // [128][64]
                             __hip_bfloat16* __restrict__ Wc2t,  // [128][64]
                             float* __restrict__ bc1, float* __restrict__ bc2,
                             __hip_bfloat16* __restrict__ Wt2,   // [128][384]
                             __hip_bfloat16* __restrict__ WtZ,
                             __hip_bfloat16* __restrict__ WtM1,
                             __hip_bfloat16* __restrict__ WtM2,
                             float* __restrict__ b2cat) {
    int idx = blockIdx.x * blockDim.x + threadIdx.x;
    if (idx < 128 * 64) {
        int c = idx >> 6, k = idx & 63;          // Wc*t[c][k], k over 64 input dims
        float s1 = 0.f, s2 = 0.f;
#pragma unroll 4
        for (int j = 0; j < 128; ++j) {
            float w = W_in[k * 128 + j];
            float wc = (c < 64) ? W1p[j * 64 + c] : W1n[j * 64 + (c - 64)];
            float wl = (c < 64) ? W1p[(128 + j) * 64 + c] : W1n[(128 + j) * 64 + (c - 64)];
            s1 += w * wc;
            s2 += w * wl;
        }
        Wc1t[idx] = __float2bfloat16(s1);
        Wc2t[idx] = __float2bfloat16(s2);
    }
    if (idx < 128 * 128) {
        int c = idx >> 7, k = idx & 127;
        WtZ[idx]  = __float2bfloat16(Wz[k * 128 + c]);
        WtM1[idx] = __float2bfloat16(Wm1[k * 128 + c]);
        WtM2[idx] = __float2bfloat16(Wm2[k * 128 + c]);
    }
    if (idx < 128 * 384) {
        int c = idx / 384, r = idx % 384;
        float v = 0.f;
        if (r < 64)       { if (c < 64)  v = W2p[r * 64 + c]; }
        else if (r < 128) { if (c >= 64) v = W2n[(r - 64) * 64 + (c - 64)]; }
        else if (r < 192) { if (c >= 64) v = W2n[(64 + r - 128) * 64 + (c - 64)]; }
        else if (r < 256) { if (c < 64)  v = W2p[(64 + r - 192) * 64 + c]; }
        else if (r < 320) { if (c < 64)  v = W2p[(128 + r - 256) * 64 + c]; }
        else              { if (c >= 64) v = W2n[(128 + r - 320) * 64 + (c - 64)]; }
        Wt2[idx] = __float2bfloat16(v);
    }
    if (idx < 128) {
        int c = idx;
        float s1 = 0.f, s2 = 0.f;
#pragma unroll 4
        for (int j = 0; j < 128; ++j) {
            float b = b_in[j];
            float wc = (c < 64) ? W1p[j * 64 + c] : W1n[j * 64 + (c - 64)];
            float wl = (c < 64) ? W1p[(128 + j) * 64 + c] : W1n[(128 + j) * 64 + (c - 64)];
            s1 += b * wc;
            s2 += b * wl;
        }
        bc1[c] = s1;
        bc2[c] = s2 + ((c < 64) ? b1p[c] : b1n[c - 64]);
        b2cat[c] = (c < 64) ? b2p[c] : b2n[c - 64];
    }
}

// ========== tile-looped pipelined MFMA GEMM: 64-row tiles, 16 rows/wave ==========
// W staged to LDS ONCE per block (async); A double-buffered in LDS; tile t+1's
// A-stage issued right after the barrier so it overlaps tile t's MFMA+epilogue;
// the end-of-iteration __syncthreads drains loads that already had a full compute
// phase to land. Fragment-ordered slots -> contiguous conflict-free ds_read_b128.
template<int K, bool AF32, bool BIAS, bool TANH_ACT, bool ADDEND,
         bool BNIN, bool STATS, bool STOREF, bool STOREB>
__global__ __launch_bounds__(256, 2) void sgemm_loop(
    const void* __restrict__ A, const __hip_bfloat16* __restrict__ Wt,  // [128][K]
    const float* __restrict__ bias,
    const float* __restrict__ addend,        // n x 128 f32
    const float* __restrict__ scale, const float* __restrict__ shift,
    double* __restrict__ stats,
    float* __restrict__ outf, __hip_bfloat16* __restrict__ outb,
    int n, int nt, int grid)
{
    constexpr int NFC = K / 32;                 // 2 (K=64) or 4 (K=128)
    constexpr int WSLOT = 8 * NFC * 64;         // W 16B slots
    constexpr int ASLOT = 1024;                 // A 16B slots per buffer (16KB)
    __shared__ __align__(16) char wlds[WSLOT * 16];
    __shared__ __align__(16) char alds[2][ASLOT * 16];
    __shared__ float ssum[128], ssq[128];
    const int tid = threadIdx.x, lane = tid & 63, wv = tid >> 6;
    const int l16 = lane & 15, lhi = lane >> 4;

    if (STATS) {
        if (tid < 128) { ssum[tid] = 0.f; ssq[tid] = 0.f; }
    }

    // ---- stage W once (fragment order) ----
#pragma unroll
    for (int i = 0; i < WSLOT / 256; ++i) {
        int slot = tid + i * 256;
        int ln = slot & 63, f = slot >> 6;
        int c = f / NFC, kk = f % NFC;
        int row = c * 16 + (ln & 15);
        int gk = kk * 32 + (ln >> 4) * 8;
        async16(Wt + (size_t)row * K + gk, wlds + slot * 16);
    }

    auto stageA = [&](int tile, int bufi) {
        char* dst = alds[bufi];
        if (AF32) {   // K==64, f32 input: slot f = ((w*2+kk)*2+half)
#pragma unroll
            for (int i = 0; i < 4; ++i) {
                int slot = tid + i * 256;
                int ln = slot & 63, f = slot >> 6;
                int w = f >> 2, kk = (f >> 1) & 1, half = f & 1;
                int row = tile * 64 + w * 16 + (ln & 15);
                if (row > n - 1) row = n - 1;
                int k = kk * 32 + (ln >> 4) * 8 + half * 4;
                async16((const float*)A + (size_t)row * 64 + k, dst + slot * 16);
            }
        } else {      // bf16 input: slot f = w*NFC + kk
#pragma unroll
            for (int i = 0; i < 4; ++i) {
                int slot = tid + i * 256;
                int ln = slot & 63, f = slot >> 6;
                int w = f / NFC, kk = f % NFC;
                int row = tile * 64 + w * 16 + (ln & 15);
                if (row > n - 1) row = n - 1;
                int gk = kk * 32 + (ln >> 4) * 8;
                async16((const __hip_bfloat16*)A + (size_t)row * K + gk, dst + slot * 16);
            }
        }
    };

    auto computeT = [&](int tile, int bufi) {
        const char* ab = alds[bufi];
        f32x4 acc[8];
#pragma unroll
        for (int c = 0; c < 8; ++c)
#pragma unroll
            for (int i = 0; i < 4; ++i) acc[c][i] = 0.f;

#pragma unroll
        for (int kk = 0; kk < NFC; ++kk) {
            bf16x8 a;
            if (AF32) {
                f32x4 lo = *reinterpret_cast<const f32x4*>(
                    ab + ((((wv * 2 + kk) * 2 + 0) * 64 + lane) << 4));
                f32x4 hi = *reinterpret_cast<const f32x4*>(
                    ab + ((((wv * 2 + kk) * 2 + 1) * 64 + lane) << 4));
                a[0] = (__bf16)lo[0]; a[1] = (__bf16)lo[1];
                a[2] = (__bf16)lo[2]; a[3] = (__bf16)lo[3];
                a[4] = (__bf16)hi[0]; a[5] = (__bf16)hi[1];
                a[6] = (__bf16)hi[2]; a[7] = (__bf16)hi[3];
            } else {
                a = *reinterpret_cast<const bf16x8*>(
                    ab + (((wv * NFC + kk) * 64 + lane) << 4));
                if (BNIN) {
#pragma unroll
                    for (int j = 0; j < 8; ++j) {
                        int k = kk * 32 + lhi * 8 + j;
                        a[j] = (__bf16)fmaxf((float)a[j] * scale[k] + shift[k], 0.f);
                    }
                }
            }
#pragma unroll
            for (int c = 0; c < 8; ++c) {
                bf16x8 b = *reinterpret_cast<const bf16x8*>(
                    wlds + (((c * NFC + kk) * 64 + lane) << 4));
                acc[c] = __builtin_amdgcn_mfma_f32_16x16x32_bf16(a, b, acc[c], 0, 0, 0);
            }
        }

        // epilogue: wave owns rows tile*64 + wv*16 .. +15
        const int brow = tile * 64 + wv * 16;
#pragma unroll
        for (int c = 0; c < 8; ++c) {
            const int col = c * 16 + l16;
            const float bv = BIAS ? bias[col] : 0.f;
            float s = 0.f, q = 0.f;
#pragma unroll
            for (int r = 0; r < 4; ++r) {
                int grow = brow + lhi * 4 + r;
                bool ok = grow < n;
                float v = acc[c][r] + bv;
                if (ADDEND) { if (ok) v += addend[(size_t)grow * 128 + col]; }
                if (TANH_ACT) v = fast_tanh(v);
                if (ok) {
                    if (STOREF) outf[(size_t)grow * 128 + col] = v;
                    if (STOREB) outb[(size_t)grow * 128 + col] = __float2bfloat16(v);
                    if (STATS) { s += v; q += v * v; }
                }
            }
            if (STATS) { atomicAdd(&ssum[col], s); atomicAdd(&ssq[col], q); }
        }
    };

    int t = blockIdx.x;
    stageA(t, 0);
    __syncthreads();                 // drain W + A(t0)
    int cur = 0;
    for (; t < nt; t += grid) {
        int tn = t + grid;
        if (tn < nt) stageA(tn, cur ^ 1);   // overlaps compute below
        computeT(t, cur);
        __syncthreads();             // drains prefetch (already landed) + guards buffers
        cur ^= 1;
    }

    if (STATS) {
        if (tid < 128) {
            atomicAdd(&stats[tid],       (double)ssum[tid]);
            atomicAdd(&stats[128 + tid], (double)ssq[tid]);
        }
    }
}

// ============ round-9 chunked GEMM kept for K=384 (G4) ============
template<int K, int NSEG, bool BIAS, bool TANH_ACT, bool STOREB>
__global__ __launch_bounds__(256, 2) void sgemm384(
    const void* __restrict__ A0, const void* __restrict__ A1, const void* __restrict__ A2,
    const __hip_bfloat16* __restrict__ Wt,   // [128][K]
    const float* __restrict__ bias,
    __hip_bfloat16* __restrict__ outb, int n)
{
    constexpr int CHUNK = 128;
    constexpr int NCH = K / CHUNK;
    constexpr int NFC = 4;
    constexpr int SEGW = K / NSEG;
    constexpr int WSLOT = 8 * NFC * 64;
    constexpr int ASLOT = 8 * NFC * 64;
    __shared__ __align__(16) char wlds[WSLOT * 16];
    __shared__ __align__(16) char alds[ASLOT * 16];
    const int tid = threadIdx.x, lane = tid & 63, wid = tid >> 6;
    const int l16 = lane & 15, lhi = lane >> 4;
    const int tile = blockIdx.x;
    const int brow = tile * 128 + wid * 32;

    f32x4 acc[2][8];
#pragma unroll
    for (int t = 0; t < 2; ++t)
#pragma unroll
        for (int c = 0; c < 8; ++c)
#pragma unroll
            for (int i = 0; i < 4; ++i) acc[t][c][i] = 0.f;

#pragma unroll
    for (int ch = 0; ch < NCH; ++ch) {
#pragma unroll
        for (int i = 0; i < WSLOT / 256; ++i) {
            int slot = tid + i * 256;
            int ln = slot & 63, f = slot >> 6;
            int c = f / NFC, kk = f % NFC;
            int row = c * 16 + (ln & 15);
            int gk = ch * CHUNK + kk * 32 + (ln >> 4) * 8;
            async16(Wt + (size_t)row * K + gk, wlds + slot * 16);
        }
        const __hip_bfloat16* Aseg = (const __hip_bfloat16*)
            ((ch == 0) ? A0 : (ch == 1 ? A1 : A2));
#pragma unroll
        for (int i = 0; i < ASLOT / 256; ++i) {
            int slot = tid + i * 256;
            int ln = slot & 63, f = slot >> 6;
            int w = f / (2 * NFC);
            int rem = f % (2 * NFC);
            int t = rem / NFC, kk = rem % NFC;
            int row = tile * 128 + w * 32 + t * 16 + (ln & 15);
            if (row > n - 1) row = n - 1;
            async16(Aseg + (size_t)row * SEGW + kk * 32 + (ln >> 4) * 8,
                    alds + slot * 16);
        }
        __syncthreads();
#pragma unroll
        for (int kk = 0; kk < NFC; ++kk) {
            bf16x8 af[2];
#pragma unroll
            for (int t = 0; t < 2; ++t)
                af[t] = *reinterpret_cast<const bf16x8*>(
                    alds + ((((wid * 2 + t) * NFC + kk) * 64 + lane) << 4));
#pragma unroll
            for (int c = 0; c < 8; ++c) {
                bf16x8 b = *reinterpret_cast<const bf16x8*>(
                    wlds + (((c * NFC + kk) * 64 + lane) << 4));
                acc[0][c] = __builtin_amdgcn_mfma_f32_16x16x32_bf16(af[0], b, acc[0][c], 0, 0, 0);
                acc[1][c] = __builtin_amdgcn_mfma_f32_16x16x32_bf16(af[1], b, acc[1][c], 0, 0, 0);
            }
        }
        if (ch != NCH - 1) __syncthreads();
    }

#pragma unroll
    for (int t = 0; t < 2; ++t)
#pragma unroll
        for (int c = 0; c < 8; ++c) {
            const int col = c * 16 + l16;
            const float bv = BIAS ? bias[col] : 0.f;
#pragma unroll
            for (int r = 0; r < 4; ++r) {
                int grow = brow + t * 16 + lhi * 4 + r;
                if (grow < n) {
                    float v = acc[t][c][r] + bv;
                    if (TANH_ACT) v = fast_tanh(v);
                    if (STOREB) outb[(size_t)grow * 128 + col] = __float2bfloat16(v);
                }
            }
        }
}

// BN finalize -> scale/shift form: relu(a*scale + shift)
__global__ void bn_finalize(const double* __restrict__ stats,
                            const float* __restrict__ g, const float* __restrict__ be,
                            float* __restrict__ scale, float* __restrict__ shift, int n) {
    int c = threadIdx.x;
    if (c < 128) {
        double m = stats[c] / (double)n;
        double var = stats[128 + c] / (double)n - m * m;
        float rs = rsqrtf((float)var + 1e-5f);
        float sc = g[c] * rs;
        scale[c] = sc;
        shift[c] = be[c] - (float)m * sc;
    }
}

// prob = sigmoid( relu(M2*scale+shift) @ Wm3 + bm3 )
__global__ void gemv_prob(const __hip_bfloat16* __restrict__ M2,
                          const float* __restrict__ scale, const float* __restrict__ shift,
                          const float* __restrict__ Wm3, const float* __restrict__ bm3,
                          float* __restrict__ outp, int n) {
    int wid = (int)((blockIdx.x * (size_t)blockDim.x + threadIdx.x) >> 6);
    int lane = threadIdx.x & 63;
    if (wid >= n) return;
    float s = 0.f;
#pragma unroll
    for (int t = 0; t < 2; ++t) {
        int k = lane + t * 64;
        float a = __bfloat162float(M2[(size_t)wid * 128 + k]);
        a = fmaxf(a * scale[k] + shift[k], 0.f);
        s += a * Wm3[k];
    }
#pragma unroll
    for (int off = 32; off > 0; off >>= 1) s += __shfl_down(s, off);
    if (lane == 0) outp[wid] = 1.f / (1.f + __expf(-(s + bm3[0])));
}

extern "C" void kernel_launch(void* const* d_in, const int* in_sizes, int n_in,
                              void* d_out, int out_size, void* d_ws, size_t ws_size,
                              hipStream_t stream) {
    const float* x   = (const float*)d_in[0];
    const int*   pos = (const int*)d_in[1];
    const int*   neg = (const int*)d_in[2];
    const float* W_in = (const float*)d_in[3];
    const float* b_in = (const float*)d_in[4];
    const float* W1p = (const float*)d_in[5];
    const float* b1p = (const float*)d_in[6];
    const float* W1n = (const float*)d_in[7];
    const float* b1n = (const float*)d_in[8];
    const float* W2p = (const float*)d_in[9];
    const float* b2p = (const float*)d_in[10];
    const float* W2n = (const float*)d_in[11];
    const float* b2n = (const float*)d_in[12];
    const float* Wz  = (const float*)d_in[13];
    const float* bz  = (const float*)d_in[14];
    const float* Wm1 = (const float*)d_in[15];
    const float* bm1 = (const float*)d_in[16];
    const float* g1  = (const float*)d_in[17];
    const float* be1 = (const float*)d_in[18];
    const float* Wm2 = (const float*)d_in[19];
    const float* bm2 = (const float*)d_in[20];
    const float* g2  = (const float*)d_in[21];
    const float* be2 = (const float*)d_in[22];
    const float* Wm3 = (const float*)d_in[23];
    const float* bm3 = (const float*)d_in[24];

    char* ws = (char*)d_ws;
    size_t off = 0;
    auto carve = [&](size_t bytes) -> void* {
        void* p = (void*)(ws + off);
        off = (off + bytes + 255) & ~(size_t)255;
        return p;
    };
    const size_t NB  = (size_t)NN * 128 * sizeof(float);
    const size_t NBH = (size_t)NN * 128 * sizeof(__hip_bfloat16);
    float* slot1 = (float*)carve(NB);                     // aggC f32; later aliased by P/Q bf16
    __hip_bfloat16* slotA = (__hip_bfloat16*)carve(NBH);  // m1B
    __hip_bfloat16* slotB = (__hip_bfloat16*)carve(NBH);  // u1B -> z2B -> m2B
    __hip_bfloat16* slotC = (__hip_bfloat16*)carve(NBH);  // z1B -> zB
    int* cnt_p = (int*)carve(NN * sizeof(int));
    int* cnt_n = (int*)carve(NN * sizeof(int));
    int* off_p = (int*)carve(NN * sizeof(int));
    int* off_n = (int*)carve(NN * sizeof(int));
    int* cur_p = (int*)carve(NN * sizeof(int));
    int* cur_n = (int*)carve(NN * sizeof(int));
    int* csr_p = (int*)carve(EP * sizeof(int));
    int* csr_n = (int*)carve(EN * sizeof(int));
    int* bsum_p = (int*)carve(1024 * sizeof(int));
    int* bsum_n = (int*)carve(1024 * sizeof(int));
    __hip_bfloat16* Wc1t = (__hip_bfloat16*)carve(128 * 64 * 2);
    __hip_bfloat16* Wc2t = (__hip_bfloat16*)carve(128 * 64 * 2);
    float* bc1 = (float*)carve(128 * sizeof(float));
    float* bc2 = (float*)carve(128 * sizeof(float));
    __hip_bfloat16* Wt2  = (__hip_bfloat16*)carve(128 * 384 * 2);
    __hip_bfloat16* WtZ  = (__hip_bfloat16*)carve(128 * 128 * 2);
    __hip_bfloat16* WtM1 = (__hip_bfloat16*)carve(128 * 128 * 2);
    __hip_bfloat16* WtM2 = (__hip_bfloat16*)carve(128 * 128 * 2);
    float* b2cat = (float*)carve(128 * sizeof(float));
    double* stats1 = (double*)carve(256 * sizeof(double));
    double* stats2 = (double*)carve(256 * sizeof(double));
    float* scale1 = (float*)carve(128 * sizeof(float));
    float* shift1 = (float*)carve(128 * sizeof(float));
    float* scale2 = (float*)carve(128 * sizeof(float));
    float* shift2 = (float*)carve(128 * sizeof(float));
    (void)ws_size; (void)in_sizes; (void)n_in; (void)out_size;

    __hip_bfloat16* aggPb = (__hip_bfloat16*)slot1;       // alias: aggC dead after G3
    __hip_bfloat16* aggQb = aggPb + (size_t)NN * 128;

    float* zout = (float*)d_out;                 // N x 128 (fp32)
    float* pout = zout + (size_t)NN * 128;       // N

    const int NT64 = (NN + 63) / 64;             // 2344 tiles of 64 rows
    const int TILES128 = (NN + 127) / 128;       // 1172 (G4)
    const int G128 = 512;                        // 2 blocks/CU
    const int G64  = 768;                        // 3 blocks/CU (48KB LDS)
    const int NBLK = (NN + SCAN_BS - 1) / SCAN_BS;

    // ---- CSR build + weight prep ----
    hipMemsetAsync(cnt_p, 0, NN * sizeof(int), stream);
    hipMemsetAsync(cnt_n, 0, NN * sizeof(int), stream);
    hipMemsetAsync(stats1, 0, 256 * sizeof(double), stream);
    hipMemsetAsync(stats2, 0, 256 * sizeof(double), stream);
    count_kernel<<<(EP + 255) / 256, 256, 0, stream>>>(pos + EP, EP, cnt_p);
    count_kernel<<<(EN + 255) / 256, 256, 0, stream>>>(neg + EN, EN, cnt_n);
    scan_block<<<NBLK, SCAN_BS, 0, stream>>>(cnt_p, NN, off_p, bsum_p);
    scan_block<<<NBLK, SCAN_BS, 0, stream>>>(cnt_n, NN, off_n, bsum_n);
    scan_bsum<<<1, SCAN_BS, 0, stream>>>(bsum_p, NBLK);
    scan_bsum<<<1, SCAN_BS, 0, stream>>>(bsum_n, NBLK);
    scan_add<<<NBLK, SCAN_BS, 0, stream>>>(bsum_p, NN, off_p, cur_p);
    scan_add<<<NBLK, SCAN_BS, 0, stream>>>(bsum_n, NN, off_n, cur_n);
    fill_csr<<<(EP + 255) / 256, 256, 0, stream>>>(pos, pos + EP, EP, cur_p, csr_p);
    fill_csr<<<(EN + 255) / 256, 256, 0, stream>>>(neg, neg + EN, EN, cur_n, csr_n);
    prep_weights<<<192, 256, 0, stream>>>(W_in, b_in, W1p, b1p, W1n, b1n,
                                          W2p, b2p, W2n, b2n, Wz, Wm1, Wm2,
                                          Wc1t, Wc2t, bc1, bc2,
                                          Wt2, WtZ, WtM1, WtM2, b2cat);

    // G2': U1 = x @ Wc1 + bc1 -> u1B (slotB)   [fused G1+G2, K=64, A f32]
    sgemm_loop<64, true, true, false, false, false, false, false, true><<<G64, 256, 0, stream>>>(
        x, Wc1t, bc1, nullptr, nullptr, nullptr, nullptr, nullptr, slotB, NN, NT64, G64);

    // aggC = [mean_pos(U1[:, :64]) | mean_neg(U1[:, 64:])] -> slot1 (f32)
    gather1v<<<(NN * 16 + 255) / 256, 256, 0, stream>>>(
        slotB, off_p, cnt_p, csr_p, off_n, cnt_n, csr_n, slot1);

    // G3': z1 = tanh(aggC + x @ Wc2 + bc2) -> z1B (slotC)   [fused G1+G3, K=64]
    sgemm_loop<64, true, true, true, true, false, false, false, true><<<G64, 256, 0, stream>>>(
        x, Wc2t, bc2, slot1, nullptr, nullptr, nullptr, nullptr, slotC, NN, NT64, G64);

    // P = mean_pos(z1), Q = mean_neg(z1) -> bf16, alias slot1
    gather2v<<<(NN * 32 + 255) / 256, 256, 0, stream>>>(
        slotC, off_p, cnt_p, csr_p, off_n, cnt_n, csr_n, aggPb, aggQb);

    // G4: z2 = tanh([P|Q|z1] @ Wt2 + b2cat) -> z2B (slotB, u1 dead)   [K=384]
    sgemm384<384, 3, true, true, true><<<TILES128, 256, 0, stream>>>(
        aggPb, aggQb, slotC, Wt2, b2cat, slotB, NN);

    // G5: z = tanh(z2 @ WtZ + bz) -> zout (f32) + zB (slotC, z1 dead)
    sgemm_loop<128, false, true, true, false, false, false, true, true><<<G128, 256, 0, stream>>>(
        slotB, WtZ, bz, nullptr, nullptr, nullptr, nullptr, zout, slotC, NN, NT64, G128);

    // G6: M1 = zB @ WtM1 + bm1 -> m1B (slotA) + stats1
    sgemm_loop<128, false, true, false, false, false, true, false, true><<<G128, 256, 0, stream>>>(
        slotC, WtM1, bm1, nullptr, nullptr, nullptr, stats1, nullptr, slotA, NN, NT64, G128);
    bn_finalize<<<1, 128, 0, stream>>>(stats1, g1, be1, scale1, shift1, NN);

    // G7: M2 = relu(BN(M1)) @ WtM2 + bm2 -> m2B (slotB, z2 dead) + stats2
    sgemm_loop<128, false, true, false, false, true, true, false, true><<<G128, 256, 0, stream>>>(
        slotA, WtM2, bm2, nullptr, scale1, shift1, stats2, nullptr, slotB, NN, NT64, G128);
    bn_finalize<<<1, 128, 0, stream>>>(stats2, g2, be2, scale2, shift2, NN);

    // prob = sigmoid(relu(BN(M2)) @ Wm3 + bm3) -> d_out tail
    gemv_prob<<<(NN + 3) / 4, 256, 0, stream>>>(slotB, scale2, shift2, Wm3, bm3, pout, NN);
}